// Round 9
// baseline (231.359 us; speedup 1.0000x reference)
//
#include <hip/hip_runtime.h>
#include <hip/hip_fp16.h>

#define B_ 16
#define C_ 3
#define H_ 384
#define W_ 1280
#define HW_ (H_*W_)
#define EPS_ 1e-7f

// LEDGER: R0-R5 pinned ~110us -> bottleneck = scattered lane-request rate
// (TA/TCP). R7: RGBX-fp16 repack, 2 scatter/px -> 67.5us. R8: coalesced VMEM
// 12->8 per 2px -> 59us. Model: scatter floor ~21us; residual ~38us mostly
// VALU (26us). R9 (this): PADDED packed image kills the x-pair merge network
// (base=clamp(x0,-1,W-1) -> slots == taps always), v_rcp_f32 replaces the
// f32 divide, row1 address = row0 + stride. Pads zeroed (NaN*0 hazard).
#define WP_ 1284                        // 2 left + 1280 + 2 right (16B-align)
#define HP_ 386                         // 1 top + 384 + 1 bottom
#define NXCD_ 8

// warp2 tiling: 256 cols x 2 rows per block, 2px/thread (R8 proven shape).
#define BANDS_ (W_/256)                 // 5
#define RTILES_ (H_/2)                  // 192
#define NBLK3_ (BANDS_*RTILES_*B_)      // 15360 (div 8 -> swizzle bijective)
#define CPX3_  (NBLK3_/NXCD_)           // 1920

// pad cells per batch: top row + bottom row + 4 side cells per interior row
#define PADPB_ (2*WP_ + 4*H_)           // 4104
#define NPAD_  (B_*PADPB_)              // 65664

typedef float v2f __attribute__((ext_vector_type(2)));
typedef float v4f __attribute__((ext_vector_type(4)));

__device__ __forceinline__ v2f load2(const float* p) {
  v2f r; __builtin_memcpy(&r, p, 8); return r;
}
__device__ __forceinline__ uint4 load16u(const void* p) {
  uint4 r; __builtin_memcpy(&r, p, 16); return r;
}
__device__ __forceinline__ v4f ntload4(const float* p) {
  return __builtin_nontemporal_load((const v4f*)p);   // 16B-aligned
}
__device__ __forceinline__ void storent2(float* p, float a, float b) {
  v2f r; r.x = a; r.y = b;
  __builtin_nontemporal_store(r, (v2f*)p);            // 8B-aligned (even col)
}
__device__ __forceinline__ unsigned pack2(float a, float b) {
  __half2 h = __floats2half2_rn(a, b);
  unsigned u; __builtin_memcpy(&u, &h, 4); return u;
}

__device__ __forceinline__ void mat3mul(const float* A, const float* Bm, float* C) {
  #pragma unroll
  for (int i = 0; i < 3; i++)
    #pragma unroll
    for (int j = 0; j < 3; j++)
      C[i*3+j] = A[i*3+0]*Bm[0*3+j] + A[i*3+1]*Bm[1*3+j] + A[i*3+2]*Bm[2*3+j];
}

// M = K * R * inv(K), T = K * t for batch b.
__device__ void compute_MT(const float* __restrict__ pose,
                           const float* __restrict__ intr,
                           int b, float* M, float* T)
{
  float K[9];
  #pragma unroll
  for (int i = 0; i < 9; i++) K[i] = intr[b*9 + i];
  float aa0 = pose[b*6 + 0], aa1 = pose[b*6 + 1], aa2 = pose[b*6 + 2];
  float t0  = pose[b*6 + 3], t1  = pose[b*6 + 4], t2  = pose[b*6 + 5];

  float theta = sqrtf(aa0*aa0 + aa1*aa1 + aa2*aa2);
  float invn  = 1.0f / (theta + EPS_);
  float x = aa0*invn, y = aa1*invn, z = aa2*invn;
  float c = cosf(theta), s = sinf(theta), t = 1.0f - c;
  float R[9] = {
    t*x*x + c,   t*x*y - s*z, t*z*x + s*y,
    t*x*y + s*z, t*y*y + c,   t*y*z - s*x,
    t*z*x - s*y, t*y*z + s*x, t*z*z + c
  };

  float a = K[0], bb = K[1], cc = K[2];
  float d = K[3], e  = K[4], f  = K[5];
  float g = K[6], h  = K[7], ii = K[8];
  float A0 = e*ii - f*h, A1 = f*g - d*ii, A2 = d*h - e*g;
  float id = 1.0f / (a*A0 + bb*A1 + cc*A2);
  float iK[9] = {
    A0*id, (cc*h - bb*ii)*id, (bb*f - cc*e)*id,
    A1*id, (a*ii - cc*g)*id,  (cc*d - a*f)*id,
    A2*id, (bb*g - a*h)*id,   (a*e  - bb*d)*id
  };

  float KR[9];
  mat3mul(K, R, KR);
  mat3mul(KR, iK, M);
  T[0] = K[0]*t0 + K[1]*t1 + K[2]*t2;
  T[1] = K[3]*t0 + K[4]*t1 + K[5]*t2;
  T[2] = K[6]*t0 + K[7]*t1 + K[8]*t2;
}

// ---- Pad zeroing: border cells x 0-weight must not be NaN (ws is raw). ----
__global__ __launch_bounds__(256) void pad_kernel(unsigned long long* __restrict__ ws)
{
  int tid = blockIdx.x * 256 + threadIdx.x;
  if (tid >= NPAD_) return;
  int b = tid / PADPB_;
  int k = tid - b * PADPB_;
  int row, col;
  if (k < WP_)            { row = 0;       col = k; }
  else if (k < 2*WP_)     { row = HP_ - 1; col = k - WP_; }
  else {
    int kk = k - 2*WP_;
    row = (kk >> 2) + 1;
    int c4 = kk & 3;
    col = (c4 < 2) ? c4 : (WP_ - 4 + c4);   // {0,1,1282,1283}
  }
  ws[(size_t)(b * HP_ + row) * WP_ + col] = 0ULL;
}

// ---- Pass 1: planar f32 -> PADDED interleaved RGBX fp16 (8B/px), 4px/thr.
// nt loads (src dead after this pass); regular stores (must be cached).
__global__ __launch_bounds__(256) void repack_kernel(
    const float* __restrict__ src, uint4* __restrict__ ws)
{
  int tg = blockIdx.x * 256 + threadIdx.x;     // quad index, exact fit
  int b  = tg / (HW_/4);
  int rq = tg - b * (HW_/4);
  int p  = rq * 4;
  int y  = p / W_;
  int x  = p - y * W_;
  const float* s = src + (size_t)b * 3 * HW_ + p;
  v4f c0 = ntload4(s);
  v4f c1 = ntload4(s + HW_);
  v4f c2 = ntload4(s + 2*HW_);
  uint4 o0, o1;
  o0.x = pack2(c0.x, c1.x); o0.y = pack2(c2.x, 0.0f);   // px0
  o0.z = pack2(c0.y, c1.y); o0.w = pack2(c2.y, 0.0f);   // px1
  o1.x = pack2(c0.z, c1.z); o1.y = pack2(c2.z, 0.0f);   // px2
  o1.z = pack2(c0.w, c1.w); o1.w = pack2(c2.w, 0.0f);   // px3
  // slot of pixel (y,x): (b*HP + y+1)*WP + (x+2); x%4==0 -> slot even -> 16B ok
  size_t slot = (size_t)(b * HP_ + y + 1) * WP_ + (x + 2);
  ws[slot >> 1]       = o0;
  ws[(slot >> 1) + 1] = o1;
}

// ---- Pass 2: 2 px/thread (x-pair), 256x2 tile, XCD swizzle, padded layout.
// Per px: 2 scattered dwordx4 (structural floor); no merge network, rcp.
__global__ __launch_bounds__(256) void warp2_kernel(
    const uint4* __restrict__ pk,
    const float* __restrict__ depth,
    const float* __restrict__ pose,
    const float* __restrict__ intr,
    float* __restrict__ out)
{
  __shared__ float sp[12];

  // XCD-aware bijective swizzle, row-tile fastest within each XCD chunk.
  int l = blockIdx.x;
  int w = (l & (NXCD_-1)) * CPX3_ + (l >> 3);
  int rt   = w % RTILES_;
  int tmp  = w / RTILES_;
  int band = tmp % BANDS_;
  int b    = tmp / BANDS_;

  int t  = threadIdx.x;
  int rr = t >> 7;                  // row within the 2-row tile
  int cp = t & 127;                 // column pair
  int j0 = band * 256 + 2*cp;       // even column: pixels A=j0, B=j0+1
  int i  = rt * 2 + rr;

  // Coalesced dwordx2 depth load before the barrier (hides under M/T).
  v2f dq = load2(depth + (size_t)b * HW_ + (size_t)i * W_ + j0);

  if (t == 0) {
    float M[9], T[3];
    compute_MT(pose, intr, b, M, T);
    #pragma unroll
    for (int k = 0; k < 9; k++) sp[k] = M[k];
    #pragma unroll
    for (int k = 0; k < 3; k++) sp[9 + k] = T[k];
  }
  __syncthreads();
  float m00 = sp[0], m01 = sp[1], m02 = sp[2];
  float m10 = sp[3], m11 = sp[4], m12 = sp[5];
  float m20 = sp[6], m21 = sp[7], m22 = sp[8];
  float T0  = sp[9], T1  = sp[10], T2 = sp[11];

  float yf = (float)i;
  float bx = m01*yf + m02;
  float by = m11*yf + m12;
  float bz = m21*yf + m22;

  const char* pkb = (const char*)pk;
  const float Wm1 = (float)(W_-1), Hm1 = (float)(H_-1);
  int rowbase = b * HP_;

  // ---------------- Pixel A ----------------
  float xfA = (float)j0;
  float dA  = dq.x;
  float czA = (m20*xfA + bz)*dA + T2;
  float ivA = __builtin_amdgcn_rcpf(czA + EPS_);     // ~1 ulp; err ~1e-3 out
  float pxA = ((m00*xfA + bx)*dA + T0) * ivA;
  float pyA = ((m10*xfA + by)*dA + T1) * ivA;
  float x0A = floorf(pxA), y0A = floorf(pyA);
  float fx1A = pxA - x0A, fx0A = 1.0f - fx1A;
  float fy1A = pyA - y0A, fy0A = 1.0f - fy1A;
  // masked tap weights (slots == taps by pad construction)
  float wx0A = (x0A >= 0.0f      && x0A <= Wm1) ? fx0A : 0.0f;
  float wx1A = (x0A+1.0f >= 0.0f && x0A+1.0f <= Wm1) ? fx1A : 0.0f;
  float wy0A = (y0A >= 0.0f      && y0A <= Hm1) ? fy0A : 0.0f;
  float wy1A = (y0A+1.0f >= 0.0f && y0A+1.0f <= Hm1) ? fy1A : 0.0f;
  float w00A = wx0A*wy0A, w01A = wx1A*wy0A, w10A = wx0A*wy1A, w11A = wx1A*wy1A;
  int xbA = (int)fminf(fmaxf(x0A, -1.0f), Wm1);
  int ybA = (int)fminf(fmaxf(y0A, -1.0f), Hm1);
  size_t offA0 = ((size_t)(rowbase + ybA + 1) * WP_ + (xbA + 2)) * 8;

  // ---------------- Pixel B ----------------
  float xfB = (float)(j0 + 1);
  float dB  = dq.y;
  float czB = (m20*xfB + bz)*dB + T2;
  float ivB = __builtin_amdgcn_rcpf(czB + EPS_);
  float pxB = ((m00*xfB + bx)*dB + T0) * ivB;
  float pyB = ((m10*xfB + by)*dB + T1) * ivB;
  float x0B = floorf(pxB), y0B = floorf(pyB);
  float fx1B = pxB - x0B, fx0B = 1.0f - fx1B;
  float fy1B = pyB - y0B, fy0B = 1.0f - fy1B;
  float wx0B = (x0B >= 0.0f      && x0B <= Wm1) ? fx0B : 0.0f;
  float wx1B = (x0B+1.0f >= 0.0f && x0B+1.0f <= Wm1) ? fx1B : 0.0f;
  float wy0B = (y0B >= 0.0f      && y0B <= Hm1) ? fy0B : 0.0f;
  float wy1B = (y0B+1.0f >= 0.0f && y0B+1.0f <= Hm1) ? fy1B : 0.0f;
  float w00B = wx0B*wy0B, w01B = wx1B*wy0B, w10B = wx0B*wy1B, w11B = wx1B*wy1B;
  int xbB = (int)fminf(fmaxf(x0B, -1.0f), Wm1);
  int ybB = (int)fminf(fmaxf(y0B, -1.0f), Hm1);
  size_t offB0 = ((size_t)(rowbase + ybB + 1) * WP_ + (xbB + 2)) * 8;

  // ---- 4 scattered gathers back-to-back; row1 = row0 + stride bytes ----
  uint4 RA0 = load16u(pkb + offA0);
  uint4 RA1 = load16u(pkb + offA0 + (size_t)WP_*8);
  uint4 RB0 = load16u(pkb + offB0);
  uint4 RB1 = load16u(pkb + offB0 + (size_t)WP_*8);
  __builtin_amdgcn_sched_barrier(0);

  // Unpack: dwords = [slot0:{c0,c1},{c2,pad} | slot1:{c0,c1},{c2,pad}]
  float2 A00 = __half22float2(*(const __half2*)&RA0.x);
  float  A02 = __low2float  (*(const __half2*)&RA0.y);
  float2 A01 = __half22float2(*(const __half2*)&RA0.z);
  float  A03 = __low2float  (*(const __half2*)&RA0.w);
  float2 A10 = __half22float2(*(const __half2*)&RA1.x);
  float  A12 = __low2float  (*(const __half2*)&RA1.y);
  float2 A11 = __half22float2(*(const __half2*)&RA1.z);
  float  A13 = __low2float  (*(const __half2*)&RA1.w);
  float vA0 = A00.x*w00A + A01.x*w01A + A10.x*w10A + A11.x*w11A;
  float vA1 = A00.y*w00A + A01.y*w01A + A10.y*w10A + A11.y*w11A;
  float vA2 = A02  *w00A + A03  *w01A + A12  *w10A + A13  *w11A;

  float2 B00 = __half22float2(*(const __half2*)&RB0.x);
  float  B02 = __low2float  (*(const __half2*)&RB0.y);
  float2 B01 = __half22float2(*(const __half2*)&RB0.z);
  float  B03 = __low2float  (*(const __half2*)&RB0.w);
  float2 B10 = __half22float2(*(const __half2*)&RB1.x);
  float  B12 = __low2float  (*(const __half2*)&RB1.y);
  float2 B11 = __half22float2(*(const __half2*)&RB1.z);
  float  B13 = __low2float  (*(const __half2*)&RB1.w);
  float vB0 = B00.x*w00B + B01.x*w01B + B10.x*w10B + B11.x*w11B;
  float vB1 = B00.y*w00B + B01.y*w01B + B10.y*w10B + B11.y*w11B;
  float vB2 = B02  *w00B + B03  *w01B + B12  *w10B + B13  *w11B;

  // 3 coalesced dwordx2 nt-stores (even j0 -> 8B-aligned).
  size_t sb = (size_t)b * C_ * HW_;
  size_t op = (size_t)i * W_ + j0;
  storent2(out + sb + op,                   vA0, vB0);
  storent2(out + sb + HW_ + op,             vA1, vB1);
  storent2(out + sb + 2*(size_t)HW_ + op,   vA2, vB2);
}

// ---- Fallback (ws too small): the proven R0 baseline (108.9us). ----
__global__ __launch_bounds__(256) void warp_fb_kernel(
    const float* __restrict__ src,
    const float* __restrict__ depth,
    const float* __restrict__ pose,
    const float* __restrict__ intr,
    float* __restrict__ out)
{
  __shared__ float sp[12];
  int b = blockIdx.y;
  if (threadIdx.x == 0) {
    float M[9], T[3];
    compute_MT(pose, intr, b, M, T);
    #pragma unroll
    for (int k = 0; k < 9; k++) sp[k] = M[k];
    #pragma unroll
    for (int k = 0; k < 3; k++) sp[9 + k] = T[k];
  }
  __syncthreads();
  float m00 = sp[0], m01 = sp[1], m02 = sp[2];
  float m10 = sp[3], m11 = sp[4], m12 = sp[5];
  float m20 = sp[6], m21 = sp[7], m22 = sp[8];
  float T0  = sp[9], T1  = sp[10], T2 = sp[11];

  int p = blockIdx.x * 256 + threadIdx.x;
  int j = p % W_;
  int i = p / W_;

  float d  = depth[(size_t)b * HW_ + p];
  float xf = (float)j, yf = (float)i;
  float cx = (m00*xf + m01*yf + m02)*d + T0;
  float cy = (m10*xf + m11*yf + m12)*d + T1;
  float cz = (m20*xf + m21*yf + m22)*d + T2;
  float inv = 1.0f / (cz + EPS_);
  float px = cx * inv, py = cy * inv;

  float x0f = floorf(px), y0f = floorf(py);
  float x1f = x0f + 1.0f, y1f = y0f + 1.0f;
  float wx1 = px - x0f, wx0 = 1.0f - wx1;
  float wy1 = py - y0f, wy0 = 1.0f - wy1;
  float mx0 = (x0f >= 0.0f && x0f <= (float)(W_-1)) ? 1.0f : 0.0f;
  float mx1 = (x1f >= 0.0f && x1f <= (float)(W_-1)) ? 1.0f : 0.0f;
  float my0 = (y0f >= 0.0f && y0f <= (float)(H_-1)) ? 1.0f : 0.0f;
  float my1 = (y1f >= 0.0f && y1f <= (float)(H_-1)) ? 1.0f : 0.0f;
  int xc0 = (int)fminf(fmaxf(x0f, 0.0f), (float)(W_-1));
  int xc1 = (int)fminf(fmaxf(x1f, 0.0f), (float)(W_-1));
  int yc0 = (int)fminf(fmaxf(y0f, 0.0f), (float)(H_-1));
  int yc1 = (int)fminf(fmaxf(y1f, 0.0f), (float)(H_-1));
  float w00 = wx0*wy0*mx0*my0;
  float w01 = wx1*wy0*mx1*my0;
  float w10 = wx0*wy1*mx0*my1;
  float w11 = wx1*wy1*mx1*my1;
  int base = xc0 < (W_-2) ? xc0 : (W_-2);
  bool s0 = (xc0 == base);
  bool s1 = (xc1 == base + 1);
  float wax = (s0 ? w00 : 0.0f) + (s1 ? 0.0f : w01);
  float way = (s0 ? 0.0f : w00) + (s1 ? w01 : 0.0f);
  float wbx = (s0 ? w10 : 0.0f) + (s1 ? 0.0f : w11);
  float wby = (s0 ? 0.0f : w10) + (s1 ? w11 : 0.0f);
  int rb0 = yc0*W_ + base;
  int rb1 = yc1*W_ + base;

  size_t sb = (size_t)b * C_ * HW_;
  const float* s0p = src + sb;
  const float* s1p = s0p + HW_;
  const float* s2p = s1p + HW_;
  v2f a0 = load2(s0p + rb0);
  v2f b0 = load2(s0p + rb1);
  v2f a1 = load2(s1p + rb0);
  v2f b1 = load2(s1p + rb1);
  v2f a2 = load2(s2p + rb0);
  v2f b2 = load2(s2p + rb1);
  float v0 = a0.x*wax + a0.y*way + b0.x*wbx + b0.y*wby;
  float v1 = a1.x*wax + a1.y*way + b1.x*wbx + b1.y*wby;
  float v2 = a2.x*wax + a2.y*way + b2.x*wbx + b2.y*wby;
  size_t op = (size_t)p;
  __builtin_nontemporal_store(v0, &out[sb + op]);
  __builtin_nontemporal_store(v1, &out[sb + HW_ + op]);
  __builtin_nontemporal_store(v2, &out[sb + 2*(size_t)HW_ + op]);
}

extern "C" void kernel_launch(void* const* d_in, const int* in_sizes, int n_in,
                              void* d_out, int out_size, void* d_ws, size_t ws_size,
                              hipStream_t stream) {
  const float* src   = (const float*)d_in[0];
  const float* depth = (const float*)d_in[1];
  const float* pose  = (const float*)d_in[2];
  const float* intr  = (const float*)d_in[3];
  float* out = (float*)d_out;

  const size_t need = (size_t)B_ * HP_ * WP_ * 8;   // 63.4 MB padded RGBX-fp16
  if (d_ws != nullptr && ws_size >= need) {
    pad_kernel<<<dim3((NPAD_ + 255)/256), 256, 0, stream>>>((unsigned long long*)d_ws);
    repack_kernel<<<dim3(B_*HW_/4/256), 256, 0, stream>>>(src, (uint4*)d_ws);
    warp2_kernel<<<dim3(NBLK3_), 256, 0, stream>>>((const uint4*)d_ws, depth, pose, intr, out);
  } else {
    dim3 grid(HW_ / 256, B_);
    warp_fb_kernel<<<grid, 256, 0, stream>>>(src, depth, pose, intr, out);
  }
}